// Round 8
// baseline (246.041 us; speedup 1.0000x reference)
//
#include <hip/hip_runtime.h>
#include <math.h>

#define NW 192
#define Wt 193
#define CHUNK 24           // k2 per block
#define NCH 8              // chunks per k1 row
#define NMAIN (192*NCH)    // 1536 blocks = 256 CUs x 6, zero tail

// cos(2*pi*num*rcpden) via HW cos (input in revolutions)
__device__ __forceinline__ float cos_revr(float num, float rcpden) {
    float rev = num * rcpden;
    rev = __builtin_amdgcn_fractf(rev);
    return __builtin_amdgcn_cosf(rev);
}

// ---------------- k_fused v8: grid -> win -> x -> einsum -> out ----------------
// Block b: k1 = b>>3, chunk c = b&7 (k2 in [24c, 24c+24)). 256 thr = 4 waves.
// 1536 blocks = exactly 6/CU; LDS 22.9 KB + <=85 VGPR -> 24 waves/CU (75% occ).
// Phase A: M -> buf1; win[24][64] -> buf2 (lane = channel).
// Phase B: x[p][j] into regs (lane = p, 24 active, c-quarter blocking keeps
//          peak regs ~40); barrier; write xls over win (alias, reads done).
// Phase C: P^T -> buf1 (M dead after B).
// Phase D: Chebyshev einsum, seeded ONCE for 24 steps (drift ~2e-5 << tol);
//          psum split into two 8-deep chains; part[4][12][64] aliases buf1.
__global__ __launch_bounds__(256, 6) void k_fused(const float* __restrict__ grid,
                                                  const float* __restrict__ Mw,
                                                  const float* __restrict__ P,
                                                  float* __restrict__ out) {
    __shared__ float buf1[4096];        // Ms[j][c] -> P^T[j][i] -> part[4][12][64]
    __shared__ float buf2[CHUNK * 68];  // win[p][c] -> xls[p][j]  (6528 B)

    int bx = blockIdx.x;
    int k1  = bx >> 3;                  // 0..191
    int k2s = (bx & 7) * CHUNK;         // 0..168
    int t = threadIdx.x;
    int lane = t & 63;
    int w = __builtin_amdgcn_readfirstlane(t >> 6);   // 0..3
    int jb = w * 16;

    // ---- Phase A: stage M (coalesced) + window averages ----
    #pragma unroll
    for (int r = 0; r < 4; ++r)
        ((float4*)buf1)[r * 256 + t] = ((const float4*)Mw)[r * 256 + t];
    {
        int c = lane;
        const float* gb  = grid + ((size_t)k1 * Wt + k2s) * 64 + c;
        const float* gb1 = gb + (size_t)Wt * 64;
        #pragma unroll
        for (int r = 0; r < 6; ++r) {
            int p = w * 6 + r;          // 4 waves x 6 = 24 positions
            float s = gb[p * 64] + gb[(p + 1) * 64]
                    + gb1[p * 64] + gb1[(p + 1) * 64];
            buf2[p * 68 + c] = 0.25f * s;
        }
    }
    __syncthreads();                    // sync1: M + win visible

    // ---- Phase B: x[p][j] into regs (lane = p, wave w -> 16 j) ----
    float accj[16];
    if (lane < CHUNK) {
        #pragma unroll
        for (int r = 0; r < 16; ++r) accj[r] = 0.f;
        #pragma unroll
        for (int q4 = 0; q4 < 4; ++q4) {        // c-quarters: peak regs ~40
            float4 wv0 = *(const float4*)&buf2[lane * 68 + q4 * 16];
            float4 wv1 = *(const float4*)&buf2[lane * 68 + q4 * 16 + 4];
            float4 wv2 = *(const float4*)&buf2[lane * 68 + q4 * 16 + 8];
            float4 wv3 = *(const float4*)&buf2[lane * 68 + q4 * 16 + 12];
            #pragma unroll
            for (int r = 0; r < 16; ++r) {
                const float4* mrow = (const float4*)&buf1[(jb + r) * 64 + q4 * 16];
                float4 m0 = mrow[0], m1 = mrow[1], m2 = mrow[2], m3 = mrow[3];
                accj[r] += wv0.x * m0.x + wv0.y * m0.y + wv0.z * m0.z + wv0.w * m0.w
                         + wv1.x * m1.x + wv1.y * m1.y + wv1.z * m1.z + wv1.w * m1.w
                         + wv2.x * m2.x + wv2.y * m2.y + wv2.z * m2.z + wv2.w * m2.w
                         + wv3.x * m3.x + wv3.y * m3.y + wv3.z * m3.z + wv3.w * m3.w;
            }
        }
    }
    __syncthreads();                    // sync2: win + M reads done
    if (lane < CHUNK) {
        #pragma unroll
        for (int r = 0; r < 16; ++r)
            buf2[lane * 68 + jb + r] = accj[r];   // xls[p][j] over win (alias)
    }
    // ---- Phase C: P^T into buf1 (M dead): pp[j*64+i] = P[i*64+j] ----
    {
        const float4* P4 = (const float4*)P;
        #pragma unroll
        for (int s = 0; s < 4; ++s) {
            int e = s * 256 + t;        // i = e>>4, j0 = (e&15)*4
            float4 v = P4[e];
            int i = e >> 4, j0 = (e & 15) * 4;
            buf1[(j0 + 0) * 64 + i] = v.x;
            buf1[(j0 + 1) * 64 + i] = v.y;
            buf1[(j0 + 2) * 64 + i] = v.z;
            buf1[(j0 + 3) * 64 + i] = v.w;
        }
    }
    __syncthreads();                    // sync3: xls + P^T visible

    // ---- Phase D: Chebyshev einsum. Thread = (i=lane, 16 j). One seed. ----
    float A[16], c1v[16], ce[16], co[16];
    #pragma unroll
    for (int jl = 0; jl < 16; ++jl) {
        float T  = (float)(lane * 64 + jb + jl + 2);
        float rT = __builtin_amdgcn_rcpf(T);
        A[jl]   = 2.0f * cos_revr(1.0f, rT);
        c1v[jl] = cos_revr((float)k1, rT) * buf1[(jb + jl) * 64 + lane];
        ce[jl]  = cos_revr((float)k2s, rT);         // cos(k2s * theta)
        co[jl]  = cos_revr((float)(k2s - 1), rT);   // cos((k2s-1) * theta)
    }
    __syncthreads();                    // sync4: P^T reads done -> buf1 = part

    float* part = buf1;                 // [w][k2l 12][i 64]
    #pragma unroll
    for (int sub = 0; sub < 2; ++sub) {
        #pragma unroll
        for (int m = 0; m < 6; ++m) {
            {   // even step: current = ce, advance co
                int k2i = sub * 12 + 2 * m;
                const float4* xq = (const float4*)&buf2[k2i * 68 + jb];
                float4 q0 = xq[0], q1 = xq[1], q2 = xq[2], q3 = xq[3];
                float xs[16] = {q0.x, q0.y, q0.z, q0.w, q1.x, q1.y, q1.z, q1.w,
                                q2.x, q2.y, q2.z, q2.w, q3.x, q3.y, q3.z, q3.w};
                float pa = 0.f, pb = 0.f;       // two 8-deep chains (ILP)
                #pragma unroll
                for (int jl = 0; jl < 8; ++jl) {
                    pa     = fmaf(xs[jl] * c1v[jl], ce[jl], pa);
                    co[jl] = fmaf(A[jl], ce[jl], -co[jl]);
                }
                #pragma unroll
                for (int jl = 8; jl < 16; ++jl) {
                    pb     = fmaf(xs[jl] * c1v[jl], ce[jl], pb);
                    co[jl] = fmaf(A[jl], ce[jl], -co[jl]);
                }
                part[(w * 12 + 2 * m) * 64 + lane] = pa + pb;
            }
            {   // odd step: current = co, advance ce
                int k2i = sub * 12 + 2 * m + 1;
                const float4* xq = (const float4*)&buf2[k2i * 68 + jb];
                float4 q0 = xq[0], q1 = xq[1], q2 = xq[2], q3 = xq[3];
                float xs[16] = {q0.x, q0.y, q0.z, q0.w, q1.x, q1.y, q1.z, q1.w,
                                q2.x, q2.y, q2.z, q2.w, q3.x, q3.y, q3.z, q3.w};
                float pa = 0.f, pb = 0.f;
                #pragma unroll
                for (int jl = 0; jl < 8; ++jl) {
                    pa     = fmaf(xs[jl] * c1v[jl], co[jl], pa);
                    ce[jl] = fmaf(A[jl], co[jl], -ce[jl]);
                }
                #pragma unroll
                for (int jl = 8; jl < 16; ++jl) {
                    pb     = fmaf(xs[jl] * c1v[jl], co[jl], pb);
                    ce[jl] = fmaf(A[jl], co[jl], -ce[jl]);
                }
                part[(w * 12 + 2 * m + 1) * 64 + lane] = pa + pb;
            }
        }
        __syncthreads();                // partials visible
        // reduce 4 wave-partials -> out (coalesced)
        #pragma unroll
        for (int s = 0; s < 3; ++s) {
            int e = s * 256 + t;        // [0,768): k2l = e>>6, i = e&63
            float r = part[e] + part[768 + e] + part[1536 + e] + part[2304 + e];
            out[((size_t)k1 * NW + (k2s + sub * 12 + (e >> 6))) * 64 + (e & 63)] = r;
        }
        __syncthreads();                // part reusable next sub
    }
}

extern "C" void kernel_launch(void* const* d_in, const int* in_sizes, int n_in,
                              void* d_out, int out_size, void* d_ws, size_t ws_size,
                              hipStream_t stream) {
    const float* grid = (const float*)d_in[0];   // [193,193,64]
    const float* Mw   = (const float*)d_in[1];   // [64,64]
    const float* P    = (const float*)d_in[2];   // [64,64]
    float* out = (float*)d_out;                  // [36864,64]
    (void)d_ws; (void)ws_size;                   // workspace unused

    k_fused<<<NMAIN, 256, 0, stream>>>(grid, Mw, P, out);
}

// Round 9
// 94.297 us; speedup vs baseline: 2.6092x; 2.6092x over previous
//
#include <hip/hip_runtime.h>
#include <math.h>

#define NW 192
#define Wt 193
#define CHUNK 48           // k2 per block
#define NMAIN 768          // 192 k1 x 4 chunks; 512 thr -> exactly 3 blocks/CU

// cos(2*pi*num*rcpden) via HW cos (input in revolutions)
__device__ __forceinline__ float cos_revr(float num, float rcpden) {
    float rev = num * rcpden;
    rev = __builtin_amdgcn_fractf(rev);
    return __builtin_amdgcn_cosf(rev);
}

// ---------------- k_fused v9: v7 phases, 8 waves/block ----------------
// Block b: k1 = b>>2, chunk c = b&3 (k2 in [48c,48c+48)). 512 thr = 8 waves.
// 768 blocks = 3/CU (LDS 45KB); 8 waves x 3 = 24 waves/CU (75% occ).
// Wave w owns j in [8w, 8w+8) -> phase-D register arrays are 8 floats each
// (32 total vs v8's 64) -> no spill pressure under launch_bounds(512,4).
// Phase A: M -> bufB; win[48][68] -> bufA.
// Phase B: x[p][j] (lane = p, 48 active; c-quartered, peak ~30 regs) -> xls.
// Phase C: P^T -> bufA (win dead).
// Phase D: Chebyshev einsum, one seed per block (48 steps, drift ~1e-4);
//          part[8][8][64] aliases bufB (Ms dead); 6 subs of 8 k2.
__global__ __launch_bounds__(512, 4) void k_fused(const float* __restrict__ grid,
                                                  const float* __restrict__ Mw,
                                                  const float* __restrict__ P,
                                                  float* __restrict__ out) {
    __shared__ float bufA[4096];        // win[48][68] (3264) -> P^T[j][i]
    __shared__ float bufB[4096];        // Ms[j][c] -> part[8][8][64]
    __shared__ float xls[CHUNK * 68];   // x[k2l][j], stride 68 (13 KB)

    int bx = blockIdx.x;
    int k1  = bx >> 2;                  // 0..191
    int k2s = (bx & 3) * CHUNK;         // 0,48,96,144
    int t = threadIdx.x;
    int lane = t & 63;
    int w = __builtin_amdgcn_readfirstlane(t >> 6);   // 0..7
    int jb = w * 8;

    // ---- Phase A: stage M (coalesced) + window averages ----
    #pragma unroll
    for (int r = 0; r < 2; ++r)
        ((float4*)bufB)[r * 512 + t] = ((const float4*)Mw)[r * 512 + t];
    {
        int c = lane;
        const float* gb  = grid + ((size_t)k1 * Wt + k2s) * 64 + c;
        const float* gb1 = gb + (size_t)Wt * 64;
        #pragma unroll
        for (int r = 0; r < 6; ++r) {
            int p = w * 6 + r;          // 8 waves x 6 = 48 positions
            float s = gb[p * 64] + gb[(p + 1) * 64]
                    + gb1[p * 64] + gb1[(p + 1) * 64];
            bufA[p * 68 + c] = 0.25f * s;
        }
    }
    __syncthreads();                    // sync1: M + win visible

    // ---- Phase B: x[p][j] -> xls (lane = p, wave w -> 8 j; c-quartered) ----
    if (lane < CHUNK) {
        float accj[8];
        #pragma unroll
        for (int r = 0; r < 8; ++r) accj[r] = 0.f;
        #pragma unroll
        for (int q4 = 0; q4 < 4; ++q4) {
            float4 wv0 = *(const float4*)&bufA[lane * 68 + q4 * 16];
            float4 wv1 = *(const float4*)&bufA[lane * 68 + q4 * 16 + 4];
            float4 wv2 = *(const float4*)&bufA[lane * 68 + q4 * 16 + 8];
            float4 wv3 = *(const float4*)&bufA[lane * 68 + q4 * 16 + 12];
            #pragma unroll
            for (int r = 0; r < 8; ++r) {
                const float4* mrow = (const float4*)&bufB[(jb + r) * 64 + q4 * 16];
                float4 m0 = mrow[0], m1 = mrow[1], m2 = mrow[2], m3 = mrow[3];
                accj[r] += wv0.x * m0.x + wv0.y * m0.y + wv0.z * m0.z + wv0.w * m0.w
                         + wv1.x * m1.x + wv1.y * m1.y + wv1.z * m1.z + wv1.w * m1.w
                         + wv2.x * m2.x + wv2.y * m2.y + wv2.z * m2.z + wv2.w * m2.w
                         + wv3.x * m3.x + wv3.y * m3.y + wv3.z * m3.z + wv3.w * m3.w;
            }
        }
        #pragma unroll
        for (int r = 0; r < 8; ++r)
            xls[lane * 68 + jb + r] = accj[r];   // xls untouched till now
    }
    __syncthreads();                    // sync2: win + M reads done

    // ---- Phase C: P^T into bufA (win dead): pp[j*64+i] = P[i*64+j] ----
    {
        const float4* P4 = (const float4*)P;
        #pragma unroll
        for (int s = 0; s < 2; ++s) {
            int e = s * 512 + t;        // [0,1024): i = e>>4, j0 = (e&15)*4
            float4 v = P4[e];
            int i = e >> 4, j0 = (e & 15) * 4;
            bufA[(j0 + 0) * 64 + i] = v.x;
            bufA[(j0 + 1) * 64 + i] = v.y;
            bufA[(j0 + 2) * 64 + i] = v.z;
            bufA[(j0 + 3) * 64 + i] = v.w;
        }
    }
    __syncthreads();                    // sync3: xls + P^T visible

    // ---- Phase D: Chebyshev einsum. Thread = (i=lane, 8 j). One seed. ----
    float A[8], c1v[8], ce[8], co[8];
    #pragma unroll
    for (int jl = 0; jl < 8; ++jl) {
        float T  = (float)(lane * 64 + jb + jl + 2);
        float rT = __builtin_amdgcn_rcpf(T);
        A[jl]   = 2.0f * cos_revr(1.0f, rT);
        c1v[jl] = cos_revr((float)k1, rT) * bufA[(jb + jl) * 64 + lane];
        ce[jl]  = cos_revr((float)k2s, rT);         // cos(k2s * theta)
        co[jl]  = cos_revr((float)(k2s - 1), rT);   // cos((k2s-1) * theta)
    }
    // part aliases bufB: Ms reads all completed at sync2; first part write
    // happens after sync3, so no extra barrier needed.
    float* part = bufB;                 // [w][k2l 8][i 64]

    #pragma unroll
    for (int sub = 0; sub < 6; ++sub) {
        #pragma unroll
        for (int m = 0; m < 4; ++m) {
            {   // even step: current = ce, advance co
                int k2i = sub * 8 + 2 * m;
                const float4* xq = (const float4*)&xls[k2i * 68 + jb];
                float4 q0 = xq[0], q1 = xq[1];
                float xs[8] = {q0.x, q0.y, q0.z, q0.w, q1.x, q1.y, q1.z, q1.w};
                float pa = 0.f, pb = 0.f;       // two 4-deep chains
                #pragma unroll
                for (int jl = 0; jl < 4; ++jl) {
                    pa     = fmaf(xs[jl] * c1v[jl], ce[jl], pa);
                    co[jl] = fmaf(A[jl], ce[jl], -co[jl]);
                }
                #pragma unroll
                for (int jl = 4; jl < 8; ++jl) {
                    pb     = fmaf(xs[jl] * c1v[jl], ce[jl], pb);
                    co[jl] = fmaf(A[jl], ce[jl], -co[jl]);
                }
                part[(w * 8 + 2 * m) * 64 + lane] = pa + pb;
            }
            {   // odd step: current = co, advance ce
                int k2i = sub * 8 + 2 * m + 1;
                const float4* xq = (const float4*)&xls[k2i * 68 + jb];
                float4 q0 = xq[0], q1 = xq[1];
                float xs[8] = {q0.x, q0.y, q0.z, q0.w, q1.x, q1.y, q1.z, q1.w};
                float pa = 0.f, pb = 0.f;
                #pragma unroll
                for (int jl = 0; jl < 4; ++jl) {
                    pa     = fmaf(xs[jl] * c1v[jl], co[jl], pa);
                    ce[jl] = fmaf(A[jl], co[jl], -ce[jl]);
                }
                #pragma unroll
                for (int jl = 4; jl < 8; ++jl) {
                    pb     = fmaf(xs[jl] * c1v[jl], co[jl], pb);
                    ce[jl] = fmaf(A[jl], co[jl], -ce[jl]);
                }
                part[(w * 8 + 2 * m + 1) * 64 + lane] = pa + pb;
            }
        }
        __syncthreads();                // partials visible
        // reduce 8 wave-partials -> out; one output per thread, coalesced
        {
            int k2l = t >> 6, i = t & 63;
            float r = 0.f;
            #pragma unroll
            for (int ww = 0; ww < 8; ++ww)
                r += part[ww * 512 + k2l * 64 + i];
            out[((size_t)k1 * NW + (k2s + sub * 8 + k2l)) * 64 + i] = r;
        }
        __syncthreads();                // part reusable next sub
    }
}

extern "C" void kernel_launch(void* const* d_in, const int* in_sizes, int n_in,
                              void* d_out, int out_size, void* d_ws, size_t ws_size,
                              hipStream_t stream) {
    const float* grid = (const float*)d_in[0];   // [193,193,64]
    const float* Mw   = (const float*)d_in[1];   // [64,64]
    const float* P    = (const float*)d_in[2];   // [64,64]
    float* out = (float*)d_out;                  // [36864,64]
    (void)d_ws; (void)ws_size;                   // workspace unused

    k_fused<<<NMAIN, 512, 0, stream>>>(grid, Mw, P, out);
}